// Round 18
// baseline (114.362 us; speedup 1.0000x reference)
//
#include <hip/hip_runtime.h>
#include <hip/hip_bf16.h>

typedef float  f32x4  __attribute__((ext_vector_type(4)));
typedef short  bf16x8 __attribute__((ext_vector_type(8)));

#define NT      16384            // BATCH*SEQ tokens
#define NBLOCK  256              // 512-thr blocks; 128KB LDS -> 1 block/CU
#define TPS     (NT / NBLOCK)    // 64 tokens per block, strided by NBLOCK
#define RING    4                // X ring: producer runs 3 tokens ahead (depth 2-3)

__device__ __forceinline__ short f2bf(float x) {
  return (short)__builtin_bit_cast(unsigned short, __float2bfloat16(x));
}
__device__ __forceinline__ unsigned packbf2(float a, float b) {
  return (unsigned)(unsigned short)f2bf(a) | ((unsigned)(unsigned short)f2bf(b) << 16);
}

__device__ __forceinline__ void gload16(const float* gp, float* lp) {
  __builtin_amdgcn_global_load_lds((const __attribute__((address_space(1))) void*)gp,
                                   (__attribute__((address_space(3))) void*)lp,
                                   16, 0, 0);
}
__device__ __forceinline__ unsigned ldsaddr(const void* p) {
  return (unsigned)(uintptr_t)(const __attribute__((address_space(3))) void*)p;
}

// Producer wave j stages chunks q=4j..4j+3 of one token's X (4 x 1KB gloads).
// Global-side XOR swizzle (16B chunks, chunk ^= row&7): proven 0 conflicts.
__device__ __forceinline__ void stageQW(float* XB, const float* gbase, int j, int lane) {
#pragma unroll
  for (int qq = 0; qq < 4; ++qq) {
    const int q = j * 4 + qq;
    const int i = q * 4 + (lane >> 4);
    const float* gp = gbase + i * 64 + (((lane & 15) ^ (i & 7)) << 2);
    gload16(gp, XB + q * 256);
  }
}

__global__ __launch_bounds__(512, 1)
void kron_kernel(const float* __restrict__ x,
                 const float* __restrict__ A,
                 const float* __restrict__ Bm,
                 const float* __restrict__ bias,
                 float* __restrict__ out) {
  // Single barrier per token. Consumer interval: stage2(k-1) FIRST (compiler
  // LDS loads on a drained slate -- avoids R16's lgkmcnt(0) interference with
  // outstanding asm ds_reads), then xf(k) asm reads -> stage1(k). Producer
  // keeps 2-3 tokens in flight (R15 depth) with one wait per interval.
  __shared__ float  xb[RING][4096];          // 64KB X ring
  __shared__ bf16x8 AT[1024];                // 16KB [s*8+ot*2+c][lane], sigma2 baked
  __shared__ bf16x8 BT[1024];                // 16KB [s*8+pt*2+jc][lane], sigma1
  __shared__ unsigned long long Ul[2][2048]; // 32KB U exchange, double-buffered

  const int tid  = threadIdx.x;
  const int lane = tid & 63;
  const int w    = tid >> 6;               // 0-3 consumer, 4-7 producer
  const int j    = w & 3;
  const int g    = lane >> 4;
  const int l15  = lane & 15;
  const int blk  = blockIdx.x;
  const bool consumer = (w < 4);

  // ---- one-time: operand tables + bias (consumer waves only) ----
  f32x4 bv[4];
  if (consumer) {
#pragma unroll
    for (int t = 0; t < 4; ++t) {                  // A: idx = s*8 + ot*2 + c
      const int idx = j * 4 + t;
      const int s = idx >> 3, ot = (idx & 7) >> 1, c = idx & 1;
      const int o = ot * 16 + l15;
      bf16x8 v;
#pragma unroll
      for (int e = 0; e < 8; ++e) {
        const int i = c * 32 + 4 * g + (e & 3) + 16 * (e >> 2);   // sigma2
        v[e] = f2bf(A[s * 4096 + o * 64 + i]);
      }
      AT[idx * 64 + lane] = v;
    }
#pragma unroll
    for (int t = 0; t < 4; ++t) {                  // B: idx = s*8 + pt*2 + jc
      const int idx = j * 4 + t;
      const int s = idx >> 3, pt = (idx & 7) >> 1, jc = idx & 1;
      const int p = pt * 16 + l15;
      bf16x8 v;
#pragma unroll
      for (int e = 0; e < 8; ++e)
        v[e] = f2bf(Bm[s * 4096 + p * 64 + (jc * 32 + 8 * g + e)]); // sigma1
      BT[idx * 64 + lane] = v;
    }
#pragma unroll
    for (int ot = 0; ot < 4; ++ot)
      bv[ot] = *(const f32x4*)(bias + (ot * 16 + l15) * 64 + j * 16 + 4 * g);
  }
  __syncthreads();   // tables visible; no gloads in flight yet (drain free)

  // ---- prologue: producers stage tokens 0,1,2 into ring slots 0,1,2 ----
  if (!consumer) {
    stageQW(&xb[0][0], x + ((size_t)blk << 12),                j, lane);
    stageQW(&xb[1][0], x + ((size_t)(blk + NBLOCK) << 12),     j, lane);
    stageQW(&xb[2][0], x + ((size_t)(blk + 2 * NBLOCK) << 12), j, lane);
    asm volatile("s_waitcnt vmcnt(8)" ::: "memory");   // token 0 resident
  }
  __builtin_amdgcn_s_barrier();

  const unsigned wsw = (unsigned)(2 * ((l15 >> 2) & 1));   // U slot swizzle bit
  const unsigned q2  = (unsigned)((l15 >> 2) & 1);

  for (int k = 0; k <= TPS; ++k) {
    if (consumer) {
      // ---- A. stage2(k-1) from Ul[(k-1)&1]: compiler LDS loads on a DRAINED
      // slate (previous interval ended lgkmcnt(0)) -> no forced serialization.
      if (k > 0) {
        const unsigned long long* Up = &Ul[(k - 1) & 1][0];
        f32x4 acc[4];
#pragma unroll
        for (int ot = 0; ot < 4; ++ot) acc[ot] = bv[ot];
#pragma unroll
        for (int s = 0; s < 2; ++s) {
          bf16x8 uf[2];
#pragma unroll
          for (int c = 0; c < 2; ++c)
            uf[c] = *reinterpret_cast<const bf16x8*>(
                &Up[((((s * 4 + j) * 4 + g) * 16 + l15) << 2) + 2u * ((unsigned)c ^ q2)]);
#pragma unroll
          for (int ot = 0; ot < 4; ++ot)
#pragma unroll
            for (int c = 0; c < 2; ++c)
              acc[ot] = __builtin_amdgcn_mfma_f32_16x16x32_bf16(
                  uf[c], AT[(s * 8 + ot * 2 + c) * 64 + lane], acc[ot], 0, 0, 0);
        }
        float* ob = out + ((size_t)(blk + (k - 1) * NBLOCK) << 12);
#pragma unroll
        for (int ot = 0; ot < 4; ++ot)
          *(f32x4*)(ob + (ot * 16 + l15) * 64 + j * 16 + 4 * g) = acc[ot];
      }

      // ---- B. xf(k): asm ds_reads -> drain -> cvt -> stage1(k) -> Ul[k&1] ----
      if (k < TPS) {
        const unsigned ba   = ldsaddr(&xb[k & (RING - 1)][0]);
        const unsigned base = ba + (unsigned)(j * 16 + l15) * 256u;
        const unsigned m    = (unsigned)(l15 & 7);
        f32x4 r0[2], r1[2];
#pragma unroll
        for (int jc = 0; jc < 2; ++jc) {
          const unsigned c0 = (unsigned)(8 * jc + 2 * g);
          asm volatile("ds_read_b128 %0, %1" : "=v"(r0[jc]) : "v"(base + ((c0 ^ m) << 4)) : "memory");
          asm volatile("ds_read_b128 %0, %1" : "=v"(r1[jc]) : "v"(base + (((c0 + 1u) ^ m) << 4)) : "memory");
        }
        asm volatile("s_waitcnt lgkmcnt(0)" ::: "memory");
        __builtin_amdgcn_sched_barrier(0);

        bf16x8 xf[2];
#pragma unroll
        for (int jc = 0; jc < 2; ++jc) {
          bf16x8 t;
          t[0]=f2bf(r0[jc][0]); t[1]=f2bf(r0[jc][1]); t[2]=f2bf(r0[jc][2]); t[3]=f2bf(r0[jc][3]);
          t[4]=f2bf(r1[jc][0]); t[5]=f2bf(r1[jc][1]); t[6]=f2bf(r1[jc][2]); t[7]=f2bf(r1[jc][3]);
          xf[jc] = t;
        }
        unsigned long long* Uw = &Ul[k & 1][0];
#pragma unroll
        for (int s = 0; s < 2; ++s) {
#pragma unroll
          for (int pt = 0; pt < 4; ++pt) {
            f32x4 a1 = (f32x4){0.f, 0.f, 0.f, 0.f};
#pragma unroll
            for (int jc = 0; jc < 2; ++jc)
              a1 = __builtin_amdgcn_mfma_f32_16x16x32_bf16(
                  xf[jc], BT[(s * 8 + pt * 2 + jc) * 64 + lane], a1, 0, 0, 0);
            const unsigned lo = packbf2(a1[0], a1[1]);
            const unsigned hi = packbf2(a1[2], a1[3]);
            Uw[((((s * 4 + pt) * 4 + g) * 16 + l15) << 2) + ((unsigned)j ^ wsw)] =
                ((unsigned long long)hi << 32) | lo;
          }
        }
        // Ul writes + xf reads all LDS-complete before the barrier publishes.
        asm volatile("s_waitcnt lgkmcnt(0)" ::: "memory");
        __builtin_amdgcn_sched_barrier(0);
      }
    } else {
      // ---- producer: issue token k+3 into slot freed at interval k-1; then
      // guarantee token k+1 resident. Newer-than-(k+1) tokens outstanding:
      // min(k+3,TPS-1)-(k+1) -> 2:vmcnt(8) (steady), 1:vmcnt(4), 0:vmcnt(0).
      if (k + 3 < TPS)
        stageQW(&xb[(k + 3) & (RING - 1)][0],
                x + ((size_t)(blk + (k + 3) * NBLOCK) << 12), j, lane);
      if (k + 3 < TPS)       asm volatile("s_waitcnt vmcnt(8)" ::: "memory");
      else if (k + 2 < TPS)  asm volatile("s_waitcnt vmcnt(4)" ::: "memory");
      else                   asm volatile("s_waitcnt vmcnt(0)" ::: "memory");
    }

    if (k < TPS) __builtin_amdgcn_s_barrier();   // ONE barrier per token
  }
}

extern "C" void kernel_launch(void* const* d_in, const int* in_sizes, int n_in,
                              void* d_out, int out_size, void* d_ws, size_t ws_size,
                              hipStream_t stream) {
  const float* x    = (const float*)d_in[0];
  const float* A    = (const float*)d_in[1];
  const float* B    = (const float*)d_in[2];
  const float* bias = (const float*)d_in[3];
  float* out        = (float*)d_out;
  kron_kernel<<<dim3(NBLOCK), dim3(512), 0, stream>>>(x, A, B, bias, out);
}

// Round 19
// 107.559 us; speedup vs baseline: 1.0632x; 1.0632x over previous
//
#include <hip/hip_runtime.h>
#include <hip/hip_bf16.h>

typedef float  f32x4  __attribute__((ext_vector_type(4)));
typedef short  bf16x8 __attribute__((ext_vector_type(8)));

#define NT      16384            // BATCH*SEQ tokens
#define NBLOCK  256              // 512-thr blocks; 160KB LDS -> 1 block/CU
#define TPS     (NT / NBLOCK)    // 64 tokens per block, strided by NBLOCK
#define RING    6                // X ring (tokens); pairs cycle 3 slot-pairs

__device__ __forceinline__ short f2bf(float x) {
  return (short)__builtin_bit_cast(unsigned short, __float2bfloat16(x));
}
__device__ __forceinline__ unsigned packbf2(float a, float b) {
  return (unsigned)(unsigned short)f2bf(a) | ((unsigned)(unsigned short)f2bf(b) << 16);
}

__device__ __forceinline__ void gload16(const float* gp, float* lp) {
  __builtin_amdgcn_global_load_lds((const __attribute__((address_space(1))) void*)gp,
                                   (__attribute__((address_space(3))) void*)lp,
                                   16, 0, 0);
}
__device__ __forceinline__ unsigned ldsaddr(const void* p) {
  return (unsigned)(uintptr_t)(const __attribute__((address_space(3))) void*)p;
}

// Producer wave j stages chunks q=4j..4j+3 of one token's X (4 x 1KB gloads).
// Global-side XOR swizzle (16B chunks, chunk ^= row&7): proven 0 conflicts.
__device__ __forceinline__ void stageQW(float* XB, const float* gbase, int j, int lane) {
#pragma unroll
  for (int qq = 0; qq < 4; ++qq) {
    const int q = j * 4 + qq;
    const int i = q * 4 + (lane >> 4);
    const float* gp = gbase + i * 64 + (((lane & 15) ^ (i & 7)) << 2);
    gload16(gp, XB + q * 256);
  }
}

__global__ __launch_bounds__(512, 1)
void kron_kernel(const float* __restrict__ x,
                 const float* __restrict__ A,
                 const float* __restrict__ Bm,
                 const float* __restrict__ bias,
                 float* __restrict__ out) {
  // R15 two-phase producer/consumer rhythm (proven: the producer's vmcnt wait
  // overlaps the consumer's stage2 between the barriers), amortized over TWO
  // tokens per interval -> 1 barrier per token instead of 2.
  __shared__ float  xb[RING][4096];          // 96KB X ring
  __shared__ bf16x8 AT[1024];                // 16KB [s*8+ot*2+c][lane], sigma2 baked
  __shared__ bf16x8 BT[1024];                // 16KB [s*8+pt*2+jc][lane], sigma1
  __shared__ unsigned long long Ul[2][2048]; // 32KB U exchange, one buf per sub-token

  const int tid  = threadIdx.x;
  const int lane = tid & 63;
  const int w    = tid >> 6;               // 0-3 consumer, 4-7 producer
  const int j    = w & 3;
  const int g    = lane >> 4;
  const int l15  = lane & 15;
  const int blk  = blockIdx.x;
  const bool consumer = (w < 4);

  // ---- one-time: operand tables + bias (consumer waves only) ----
  f32x4 bv[4];
  if (consumer) {
#pragma unroll
    for (int t = 0; t < 4; ++t) {                  // A: idx = s*8 + ot*2 + c
      const int idx = j * 4 + t;
      const int s = idx >> 3, ot = (idx & 7) >> 1, c = idx & 1;
      const int o = ot * 16 + l15;
      bf16x8 v;
#pragma unroll
      for (int e = 0; e < 8; ++e) {
        const int i = c * 32 + 4 * g + (e & 3) + 16 * (e >> 2);   // sigma2
        v[e] = f2bf(A[s * 4096 + o * 64 + i]);
      }
      AT[idx * 64 + lane] = v;
    }
#pragma unroll
    for (int t = 0; t < 4; ++t) {                  // B: idx = s*8 + pt*2 + jc
      const int idx = j * 4 + t;
      const int s = idx >> 3, pt = (idx & 7) >> 1, jc = idx & 1;
      const int p = pt * 16 + l15;
      bf16x8 v;
#pragma unroll
      for (int e = 0; e < 8; ++e)
        v[e] = f2bf(Bm[s * 4096 + p * 64 + (jc * 32 + 8 * g + e)]); // sigma1
      BT[idx * 64 + lane] = v;
    }
#pragma unroll
    for (int ot = 0; ot < 4; ++ot)
      bv[ot] = *(const f32x4*)(bias + (ot * 16 + l15) * 64 + j * 16 + 4 * g);
  }
  __syncthreads();   // tables visible; no gloads in flight yet (drain free)

  // ---- prologue: producers stage tokens 0..3 into ring slots 0..3 ----
  if (!consumer) {
#pragma unroll
    for (int p = 0; p < 4; ++p)
      stageQW(&xb[p][0], x + ((size_t)(blk + p * NBLOCK) << 12), j, lane);
    asm volatile("s_waitcnt vmcnt(8)" ::: "memory");   // tokens 0,1 resident
  }
  __builtin_amdgcn_s_barrier();

  const unsigned wsw = (unsigned)(2 * ((l15 >> 2) & 1));   // U slot swizzle bit
  const unsigned q2  = (unsigned)((l15 >> 2) & 1);

  for (int i = 0; i < TPS / 2; ++i) {
    const int t0 = 2 * i;            // this interval's token pair: t0, t0+1

    if (consumer) {
      // ---- phase 1: stage1 for both sub-tokens -> Ul[0], Ul[1] ----
#pragma unroll
      for (int h = 0; h < 2; ++h) {
        const int tok = t0 + h;
        const unsigned ba   = ldsaddr(&xb[tok % RING][0]);
        const unsigned base = ba + (unsigned)(j * 16 + l15) * 256u;
        const unsigned m    = (unsigned)(l15 & 7);
        f32x4 r0[2], r1[2];
#pragma unroll
        for (int jc = 0; jc < 2; ++jc) {
          const unsigned c0 = (unsigned)(8 * jc + 2 * g);
          asm volatile("ds_read_b128 %0, %1" : "=v"(r0[jc]) : "v"(base + ((c0 ^ m) << 4)) : "memory");
          asm volatile("ds_read_b128 %0, %1" : "=v"(r1[jc]) : "v"(base + (((c0 + 1u) ^ m) << 4)) : "memory");
        }
        asm volatile("s_waitcnt lgkmcnt(0)" ::: "memory");
        __builtin_amdgcn_sched_barrier(0);

        bf16x8 xf[2];
#pragma unroll
        for (int jc = 0; jc < 2; ++jc) {
          bf16x8 t;
          t[0]=f2bf(r0[jc][0]); t[1]=f2bf(r0[jc][1]); t[2]=f2bf(r0[jc][2]); t[3]=f2bf(r0[jc][3]);
          t[4]=f2bf(r1[jc][0]); t[5]=f2bf(r1[jc][1]); t[6]=f2bf(r1[jc][2]); t[7]=f2bf(r1[jc][3]);
          xf[jc] = t;
        }
        unsigned long long* Uw = &Ul[h][0];
#pragma unroll
        for (int s = 0; s < 2; ++s) {
#pragma unroll
          for (int pt = 0; pt < 4; ++pt) {
            f32x4 a1 = (f32x4){0.f, 0.f, 0.f, 0.f};
#pragma unroll
            for (int jc = 0; jc < 2; ++jc)
              a1 = __builtin_amdgcn_mfma_f32_16x16x32_bf16(
                  xf[jc], BT[(s * 8 + pt * 2 + jc) * 64 + lane], a1, 0, 0, 0);
            const unsigned lo = packbf2(a1[0], a1[1]);
            const unsigned hi = packbf2(a1[2], a1[3]);
            Uw[((((s * 4 + pt) * 4 + g) * 16 + l15) << 2) + ((unsigned)j ^ wsw)] =
                ((unsigned long long)hi << 32) | lo;
          }
        }
      }
      asm volatile("s_waitcnt lgkmcnt(0)" ::: "memory");
      __builtin_amdgcn_sched_barrier(0);
    } else {
      // ---- producer phase A: issue token pair t0+4, t0+5 (slots freed at i-1) ----
      if (t0 + 4 < TPS) {
        stageQW(&xb[(t0 + 4) % RING][0],
                x + ((size_t)(blk + (t0 + 4) * NBLOCK) << 12), j, lane);
        stageQW(&xb[(t0 + 5) % RING][0],
                x + ((size_t)(blk + (t0 + 5) * NBLOCK) << 12), j, lane);
      }
    }

    __builtin_amdgcn_s_barrier();   // barrier 1: U pair visible / ring write-safe

    if (consumer) {
      // ---- phase 2: stage2 + store for both sub-tokens ----
#pragma unroll
      for (int h = 0; h < 2; ++h) {
        const unsigned long long* Up = &Ul[h][0];
        f32x4 acc[4];
#pragma unroll
        for (int ot = 0; ot < 4; ++ot) acc[ot] = bv[ot];
#pragma unroll
        for (int s = 0; s < 2; ++s) {
          bf16x8 uf[2];
#pragma unroll
          for (int c = 0; c < 2; ++c)
            uf[c] = *reinterpret_cast<const bf16x8*>(
                &Up[((((s * 4 + j) * 4 + g) * 16 + l15) << 2) + 2u * ((unsigned)c ^ q2)]);
#pragma unroll
          for (int ot = 0; ot < 4; ++ot)
#pragma unroll
            for (int c = 0; c < 2; ++c)
              acc[ot] = __builtin_amdgcn_mfma_f32_16x16x32_bf16(
                  uf[c], AT[(s * 8 + ot * 2 + c) * 64 + lane], acc[ot], 0, 0, 0);
        }
        float* ob = out + ((size_t)(blk + (t0 + h) * NBLOCK) << 12);
#pragma unroll
        for (int ot = 0; ot < 4; ++ot)
          *(f32x4*)(ob + (ot * 16 + l15) * 64 + j * 16 + 4 * g) = acc[ot];
      }
    } else {
      // ---- producer phase B: tokens t0+2, t0+3 must be resident before
      // barrier 2. Outstanding (old->new): gl(t0+2),gl(t0+3)[,gl(t0+4),gl(t0+5)]
      // -> vmcnt(8) when the pair t0+4 was issued, else vmcnt(0).
      if (t0 + 4 < TPS) asm volatile("s_waitcnt vmcnt(8)" ::: "memory");
      else              asm volatile("s_waitcnt vmcnt(0)" ::: "memory");
    }

    __builtin_amdgcn_s_barrier();   // barrier 2: next token pair ready
  }
}

extern "C" void kernel_launch(void* const* d_in, const int* in_sizes, int n_in,
                              void* d_out, int out_size, void* d_ws, size_t ws_size,
                              hipStream_t stream) {
  const float* x    = (const float*)d_in[0];
  const float* A    = (const float*)d_in[1];
  const float* B    = (const float*)d_in[2];
  const float* bias = (const float*)d_in[3];
  float* out        = (float*)d_out;
  kron_kernel<<<dim3(NBLOCK), dim3(512), 0, stream>>>(x, A, B, bias, out);
}

// Round 20
// 101.462 us; speedup vs baseline: 1.1271x; 1.0601x over previous
//
#include <hip/hip_runtime.h>
#include <hip/hip_bf16.h>

typedef float  f32x4  __attribute__((ext_vector_type(4)));
typedef short  bf16x8 __attribute__((ext_vector_type(8)));

#define NT      16384            // BATCH*SEQ tokens
#define NBLOCK  256              // 512-thr blocks; 112KB LDS -> 1 block/CU
#define TPS     (NT / NBLOCK)    // 64 tokens per block, strided by NBLOCK

__device__ __forceinline__ short f2bf(float x) {
  return (short)__builtin_bit_cast(unsigned short, __float2bfloat16(x));
}
__device__ __forceinline__ unsigned packbf2(float a, float b) {
  return (unsigned)(unsigned short)f2bf(a) | ((unsigned)(unsigned short)f2bf(b) << 16);
}

__device__ __forceinline__ void gload16(const float* gp, float* lp) {
  __builtin_amdgcn_global_load_lds((const __attribute__((address_space(1))) void*)gp,
                                   (__attribute__((address_space(3))) void*)lp,
                                   16, 0, 0);
}
__device__ __forceinline__ unsigned ldsaddr(const void* p) {
  return (unsigned)(uintptr_t)(const __attribute__((address_space(3))) void*)p;
}

// Producer wave j stages chunks q=4j..4j+3 of one token's X (4 x 1KB gloads).
// Global-side XOR swizzle (16B chunks, chunk ^= row&7): proven 0 conflicts.
__device__ __forceinline__ void stageQW(float* XB, const float* gbase, int j, int lane) {
#pragma unroll
  for (int qq = 0; qq < 4; ++qq) {
    const int q = j * 4 + qq;
    const int i = q * 4 + (lane >> 4);
    const float* gp = gbase + i * 64 + (((lane & 15) ^ (i & 7)) << 2);
    gload16(gp, XB + q * 256);
  }
}

__global__ __launch_bounds__(512, 1)
void kron_kernel(const float* __restrict__ x,
                 const float* __restrict__ A,
                 const float* __restrict__ Bm,
                 const float* __restrict__ bias,
                 float* __restrict__ out) {
  // R15 champion structure (producer/consumer, two-barrier rhythm), plus ONE
  // change: producer waves run at s_setprio(1) through the main loop. Each
  // SIMD hosts 1 consumer + 1 producer; when a producer's vmcnt satisfies it
  // wins the next issue slots immediately, keeping the memory queue fed while
  // the consumer's MFMA/cvt burst (which has slack) yields a few cycles.
  __shared__ float  xb[4][4096];            // 64KB X ring (4 tokens)
  __shared__ bf16x8 AT[1024];               // 16KB [s*8+ot*2+c][lane], sigma2 baked
  __shared__ bf16x8 BT[1024];               // 16KB [s*8+pt*2+jc][lane], sigma1
  __shared__ unsigned long long Ul[2048];   // 16KB U exchange

  const int tid  = threadIdx.x;
  const int lane = tid & 63;
  const int w    = tid >> 6;               // 0-3 consumer, 4-7 producer
  const int j    = w & 3;
  const int g    = lane >> 4;
  const int l15  = lane & 15;
  const int blk  = blockIdx.x;
  const bool consumer = (w < 4);

  // ---- one-time: operand tables + bias (consumer waves only; 4 rows/table) ----
  f32x4 bv[4];
  if (consumer) {
#pragma unroll
    for (int t = 0; t < 4; ++t) {                  // A: idx = s*8 + ot*2 + c
      const int idx = j * 4 + t;
      const int s = idx >> 3, ot = (idx & 7) >> 1, c = idx & 1;
      const int o = ot * 16 + l15;
      bf16x8 v;
#pragma unroll
      for (int e = 0; e < 8; ++e) {
        const int i = c * 32 + 4 * g + (e & 3) + 16 * (e >> 2);   // sigma2
        v[e] = f2bf(A[s * 4096 + o * 64 + i]);
      }
      AT[idx * 64 + lane] = v;
    }
#pragma unroll
    for (int t = 0; t < 4; ++t) {                  // B: idx = s*8 + pt*2 + jc
      const int idx = j * 4 + t;
      const int s = idx >> 3, pt = (idx & 7) >> 1, jc = idx & 1;
      const int p = pt * 16 + l15;
      bf16x8 v;
#pragma unroll
      for (int e = 0; e < 8; ++e)
        v[e] = f2bf(Bm[s * 4096 + p * 64 + (jc * 32 + 8 * g + e)]); // sigma1
      BT[idx * 64 + lane] = v;
    }
#pragma unroll
    for (int ot = 0; ot < 4; ++ot)
      bv[ot] = *(const f32x4*)(bias + (ot * 16 + l15) * 64 + j * 16 + 4 * g);
  }
  __syncthreads();   // tables visible; full drain is free here (no gloads yet)

  // ---- prologue: producers stage tokens 0,1,2 into ring slots 0,1,2 ----
  if (!consumer) {
    stageQW(&xb[0][0], x + ((size_t)blk << 12),                j, lane);
    stageQW(&xb[1][0], x + ((size_t)(blk + NBLOCK) << 12),     j, lane);
    stageQW(&xb[2][0], x + ((size_t)(blk + 2 * NBLOCK) << 12), j, lane);
    asm volatile("s_waitcnt vmcnt(8)" ::: "memory");   // token 0 resident
    __builtin_amdgcn_s_setprio(1);   // producers win issue arbitration
  }
  __builtin_amdgcn_s_barrier();

  const unsigned wsw = (unsigned)(2 * ((l15 >> 2) & 1));   // U slot swizzle bit

  for (int k = 0; k < TPS; ++k) {
    if (consumer) {
      // ---- 1. xf for it=j from ring[k&3] (asm ds_read, waitcnt-invisible) ----
      const unsigned ba   = ldsaddr(&xb[k & 3][0]);
      const unsigned base = ba + (unsigned)(j * 16 + l15) * 256u;
      const unsigned m    = (unsigned)(l15 & 7);
      f32x4 r0[2], r1[2];
#pragma unroll
      for (int jc = 0; jc < 2; ++jc) {
        const unsigned c0 = (unsigned)(8 * jc + 2 * g);
        asm volatile("ds_read_b128 %0, %1" : "=v"(r0[jc]) : "v"(base + ((c0 ^ m) << 4)) : "memory");
        asm volatile("ds_read_b128 %0, %1" : "=v"(r1[jc]) : "v"(base + (((c0 + 1u) ^ m) << 4)) : "memory");
      }
      asm volatile("s_waitcnt lgkmcnt(0)" ::: "memory");
      __builtin_amdgcn_sched_barrier(0);

      bf16x8 xf[2];
#pragma unroll
      for (int jc = 0; jc < 2; ++jc) {
        bf16x8 t;
        t[0]=f2bf(r0[jc][0]); t[1]=f2bf(r0[jc][1]); t[2]=f2bf(r0[jc][2]); t[3]=f2bf(r0[jc][3]);
        t[4]=f2bf(r1[jc][0]); t[5]=f2bf(r1[jc][1]); t[6]=f2bf(r1[jc][2]); t[7]=f2bf(r1[jc][3]);
        xf[jc] = t;
      }

      // ---- 2. stage 1 (it=j, all pt, both s): U tiles -> LDS exchange ----
#pragma unroll
      for (int s = 0; s < 2; ++s) {
#pragma unroll
        for (int pt = 0; pt < 4; ++pt) {
          f32x4 a1 = (f32x4){0.f, 0.f, 0.f, 0.f};
#pragma unroll
          for (int jc = 0; jc < 2; ++jc)
            a1 = __builtin_amdgcn_mfma_f32_16x16x32_bf16(
                xf[jc], BT[(s * 8 + pt * 2 + jc) * 64 + lane], a1, 0, 0, 0);
          const unsigned lo = packbf2(a1[0], a1[1]);
          const unsigned hi = packbf2(a1[2], a1[3]);
          Ul[((((s * 4 + pt) * 4 + g) * 16 + l15) << 2) + ((unsigned)j ^ wsw)] =
              ((unsigned long long)hi << 32) | lo;
        }
      }
      asm volatile("s_waitcnt lgkmcnt(0)" ::: "memory");
      __builtin_amdgcn_sched_barrier(0);
    } else {
      // ---- producer phase A: issue token k+3 into the slot freed at k-1 ----
      if (k + 3 < TPS)
        stageQW(&xb[(k + 3) & 3][0],
                x + ((size_t)(blk + (k + 3) * NBLOCK) << 12), j, lane);
    }

    __builtin_amdgcn_s_barrier();   // barrier 1: U visible / ring write-safe

    if (consumer) {
      // ---- 3. stage 2 (pt=j, all ot, both s) + store ----
      f32x4 acc[4];
#pragma unroll
      for (int ot = 0; ot < 4; ++ot) acc[ot] = bv[ot];
#pragma unroll
      for (int s = 0; s < 2; ++s) {
        bf16x8 uf[2];
#pragma unroll
        for (int c = 0; c < 2; ++c) {
          const unsigned q2 = (unsigned)((l15 >> 2) & 1);
          uf[c] = *reinterpret_cast<const bf16x8*>(
              &Ul[((((s * 4 + j) * 4 + g) * 16 + l15) << 2) + 2u * ((unsigned)c ^ q2)]);
        }
#pragma unroll
        for (int ot = 0; ot < 4; ++ot)
#pragma unroll
          for (int c = 0; c < 2; ++c)
            acc[ot] = __builtin_amdgcn_mfma_f32_16x16x32_bf16(
                uf[c], AT[(s * 8 + ot * 2 + c) * 64 + lane], acc[ot], 0, 0, 0);
      }
      float* ob = out + ((size_t)(blk + k * NBLOCK) << 12);
#pragma unroll
      for (int ot = 0; ot < 4; ++ot)
        *(f32x4*)(ob + (ot * 16 + l15) * 64 + j * 16 + 4 * g) = acc[ot];
    } else {
      // ---- producer phase B: ensure token k+1 resident before barrier 2.
      // Outstanding per producer: tokens k+1..min(k+3,TPS-1), 4 gloads each.
      if (k < TPS - 3)       asm volatile("s_waitcnt vmcnt(8)" ::: "memory");
      else if (k == TPS - 3) asm volatile("s_waitcnt vmcnt(4)" ::: "memory");
      else                   asm volatile("s_waitcnt vmcnt(0)" ::: "memory");
    }

    __builtin_amdgcn_s_barrier();   // barrier 2: token k+1 ready, k consumed
  }
}

extern "C" void kernel_launch(void* const* d_in, const int* in_sizes, int n_in,
                              void* d_out, int out_size, void* d_ws, size_t ws_size,
                              hipStream_t stream) {
  const float* x    = (const float*)d_in[0];
  const float* A    = (const float*)d_in[1];
  const float* B    = (const float*)d_in[2];
  const float* bias = (const float*)d_in[3];
  float* out        = (float*)d_out;
  kron_kernel<<<dim3(NBLOCK), dim3(512), 0, stream>>>(x, A, B, bias, out);
}